// Round 20
// baseline (113.343 us; speedup 1.0000x reference)
//
#include <hip/hip_runtime.h>
#include <hip/hip_bf16.h>
#include <stdint.h>

#define D_MODEL 256
#define NHEAD   8
#define DK      32
#define BATCH   4
#define SEQ     2048
#define MROWS   (BATCH*SEQ)   // 8192

typedef float  f32x4  __attribute__((ext_vector_type(4)));
typedef __bf16 bf16x8 __attribute__((ext_vector_type(8)));

__device__ __forceinline__ unsigned short f2bf(float f) {
  unsigned int u = __float_as_uint(f);
  unsigned int r = (u + 0x7FFFu + ((u >> 16) & 1u)) >> 16;
  return (unsigned short)r;
}
__device__ __forceinline__ float bfbits2f(unsigned short b) {
  return __uint_as_float(((unsigned int)b) << 16);
}

__device__ __forceinline__ f32x4 mfma16(bf16x8 a, bf16x8 b, f32x4 c) {
  return __builtin_amdgcn_mfma_f32_16x16x32_bf16(a, b, c, 0, 0, 0);
}
// packed f32->bf16 pair via plain integer ops (RNE, identical rounding to
// f2bf/cvt_pk — r1<->r4 equivalence); no inline asm, no special types.
__device__ __forceinline__ unsigned int pk2(float lo, float hi) {
  return ((unsigned int)f2bf(hi) << 16) | (unsigned int)f2bf(lo);
}

// scale folded into Wq/bq: (1/sqrt(32)) * log2(e)
#define QSCALE 0.2550599440097021f

// ---------------- fused QKV projection GEMM (128x64 tiles) -------------------
// y -> mat = y>>2 (0=Q,1=K,2=V), ncol=(y&3)*64. W casts fused into B staging;
// x cast fused into A staging. Q/K out: [bh][s][32]; V out: transposed +
// w-scaled: Vt[bh][d][s] = w_s*V[s][d]. y==0 blocks also materialize wb[].
__global__ __launch_bounds__(256) void qkv_gemm(
    const float* __restrict__ x, const float* __restrict__ cx,
    const float* __restrict__ Wq, const float* __restrict__ Wk,
    const float* __restrict__ Wv,
    const float* __restrict__ bq, const float* __restrict__ bk_, const float* __restrict__ bv,
    unsigned short* __restrict__ Qb, unsigned short* __restrict__ Kb,
    unsigned short* __restrict__ Vt, unsigned short* __restrict__ wb) {
  __shared__ __align__(16) unsigned short As[128 * 72];
  __shared__ __align__(16) unsigned short Bs[64 * 72];
  const int tid = threadIdx.x, lane = tid & 63, wid = tid >> 6;
  const int bm = blockIdx.x * 128;
  const int mat = blockIdx.y >> 2;
  const int ncol = (blockIdx.y & 3) * 64;
  const float* Wf = (mat == 0) ? Wq : ((mat == 1) ? Wk : Wv);
  const float* bias = (mat == 0) ? bq : ((mat == 1) ? bk_ : bv);
  const float bscale = (mat == 0) ? QSCALE : 1.0f;
  const int waveM = wid * 32;

  if (blockIdx.y == 0 && tid < 32) {
    int s = blockIdx.x * 32 + tid;
    wb[s] = (s == 0) ? (unsigned short)0 : f2bf(fabsf(cx[s] - cx[s - 1]));
  }

  f32x4 acc[2][4] = {};
  for (int kt = 0; kt < 4; ++kt) {
    __syncthreads();
#pragma unroll
    for (int p = 0; p < 4; ++p) {
      int c = p * 256 + tid;
      int r = c >> 3, kc = c & 7;
      const float* xp = x + (size_t)(bm + r) * 256 + kt * 64 + kc * 8;
      float4 f0 = *reinterpret_cast<const float4*>(xp);
      float4 f1 = *reinterpret_cast<const float4*>(xp + 4);
      ushort4 h0, h1;
      h0.x = f2bf(f0.x); h0.y = f2bf(f0.y); h0.z = f2bf(f0.z); h0.w = f2bf(f0.w);
      h1.x = f2bf(f1.x); h1.y = f2bf(f1.y); h1.z = f2bf(f1.z); h1.w = f2bf(f1.w);
      *reinterpret_cast<ushort4*>(&As[r * 72 + kc * 8])     = h0;
      *reinterpret_cast<ushort4*>(&As[r * 72 + kc * 8 + 4]) = h1;
    }
#pragma unroll
    for (int p = 0; p < 2; ++p) {
      int c = p * 256 + tid;
      int r = c >> 3, kc = c & 7;
      const float* wp_ = Wf + (size_t)(ncol + r) * 256 + kt * 64 + kc * 8;
      float4 g0 = *reinterpret_cast<const float4*>(wp_);
      float4 g1 = *reinterpret_cast<const float4*>(wp_ + 4);
      ushort4 b0, b1;
      b0.x = f2bf(g0.x * bscale); b0.y = f2bf(g0.y * bscale);
      b0.z = f2bf(g0.z * bscale); b0.w = f2bf(g0.w * bscale);
      b1.x = f2bf(g1.x * bscale); b1.y = f2bf(g1.y * bscale);
      b1.z = f2bf(g1.z * bscale); b1.w = f2bf(g1.w * bscale);
      *reinterpret_cast<ushort4*>(&Bs[r * 72 + kc * 8])     = b0;
      *reinterpret_cast<ushort4*>(&Bs[r * 72 + kc * 8 + 4]) = b1;
    }
    __syncthreads();
#pragma unroll
    for (int ks = 0; ks < 2; ++ks) {
      bf16x8 af[2], bf[4];
#pragma unroll
      for (int m = 0; m < 2; ++m)
        af[m] = *reinterpret_cast<const bf16x8*>(&As[(waveM + m * 16 + (lane & 15)) * 72 + ks * 32 + (lane >> 4) * 8]);
#pragma unroll
      for (int n = 0; n < 4; ++n)
        bf[n] = *reinterpret_cast<const bf16x8*>(&Bs[(n * 16 + (lane & 15)) * 72 + ks * 32 + (lane >> 4) * 8]);
#pragma unroll
      for (int m = 0; m < 2; ++m)
#pragma unroll
        for (int n = 0; n < 4; ++n) acc[m][n] = mfma16(af[m], bf[n], acc[m][n]);
    }
  }
#pragma unroll
  for (int m = 0; m < 2; ++m) {
    int i0 = bm + waveM + m * 16 + (lane >> 4) * 4;  // row of r=0 (mult of 4)
    int b = i0 >> 11, s = i0 & 2047;
    float wv4[4] = {0.f, 0.f, 0.f, 0.f};
    if (mat == 2) {
      float cm = (s > 0) ? cx[s - 1] : 0.0f;
      float c0 = cx[s], c1 = cx[s + 1], c2 = cx[s + 2], c3 = cx[s + 3];
      wv4[0] = (s > 0) ? bfbits2f(f2bf(fabsf(c0 - cm))) : 0.0f;
      wv4[1] = bfbits2f(f2bf(fabsf(c1 - c0)));
      wv4[2] = bfbits2f(f2bf(fabsf(c2 - c1)));
      wv4[3] = bfbits2f(f2bf(fabsf(c3 - c2)));
    }
#pragma unroll
    for (int n = 0; n < 4; ++n) {
      int j = ncol + n * 16 + (lane & 15);
      float bias_v = bias[j] * bscale;
      int h = j >> 5, d = j & 31;
      if (mat == 2) {
        ushort4 pk;
        pk.x = f2bf((acc[m][n][0] + bias_v) * wv4[0]);
        pk.y = f2bf((acc[m][n][1] + bias_v) * wv4[1]);
        pk.z = f2bf((acc[m][n][2] + bias_v) * wv4[2]);
        pk.w = f2bf((acc[m][n][3] + bias_v) * wv4[3]);
        *reinterpret_cast<ushort4*>(&Vt[((b * NHEAD + h) * DK + d) * SEQ + s]) = pk;
      } else {
        unsigned short* dst = (mat == 0) ? Qb : Kb;
#pragma unroll
        for (int r = 0; r < 4; ++r)
          dst[((b * NHEAD + h) * SEQ + s + r) * DK + d] = f2bf(acc[m][n][r] + bias_v);
      }
    }
  }
}

// ---------------- fused weighted attention (P consumed in situ as B operand) -
// QK identical to r8/r18 (HW-validated): lane (g,lq) gets sc0[r]=P[s0+4g+r][q],
// sc1[r]=P[s0+16+4g+r][q], q=16m+lq. Packed IN THAT ORDER the lane's 8 values
// form the PV B-fragment for q=lq with element labeling sigma(g,e) = s0+4g+e
// (e<4) / s0+16+4g+(e-4) (e>=4). V and w are loaded as A-operands with the
// SAME labeling (two b64 loads per d-row) -> by the r8-validated symmetric
// pairing, o = mfma(V_A, P_B) computes out[d][q] with NO LDS transport at all.
// XCD-affinity grid kept from r18 (FETCH 34.8->6.2MB, K/V L2-resident).
__global__ __launch_bounds__(256, 4) void attn_kernel(
    const unsigned short* __restrict__ Qb, const unsigned short* __restrict__ Kb,
    const unsigned short* __restrict__ Vt, const unsigned short* __restrict__ wb,
    unsigned short* __restrict__ AOb) {
  __shared__ float ol[4][32][36];
  const int tid = threadIdx.x, lane = tid & 63, wid = tid >> 6;
  const int g = lane >> 4, lq = lane & 15;

  // XCD-affinity decode: xcd = bid%8 serves bh in [4*xcd, 4*xcd+4)
  const int bid = blockIdx.x;
  const int xcd = bid & 7, slot = bid >> 3;        // 256 slots per XCD
  const int bh = xcd * 4 + (slot >> 6);
  const int q0 = (slot & 63) * 32;

  const unsigned short* Qbh = Qb + bh * SEQ * DK;
  const unsigned short* Kbh = Kb + bh * SEQ * DK;
  const unsigned short* Vbh = Vt + bh * DK * SEQ;

  bf16x8 qf[2];
  qf[0] = *reinterpret_cast<const bf16x8*>(Qbh + (q0 + lq) * DK + g * 8);
  qf[1] = *reinterpret_cast<const bf16x8*>(Qbh + (q0 + 16 + lq) * DK + g * 8);

  f32x4 o[2][2] = {};   // [q-tile m][d-tile n]; lane: out[d=16n+4g+r][q=16m+lq]
  f32x4 den[2] = {};
  const f32x4 zero4 = {0.f, 0.f, 0.f, 0.f};
  const int sbase = wid * (SEQ / 4);

#pragma unroll 2
  for (int st = 0; st < (SEQ / 4) / 32; ++st) {
    const int s0 = sbase + st * 32;
    bf16x8 kf0 = *reinterpret_cast<const bf16x8*>(Kbh + (s0 + lq) * DK + g * 8);
    bf16x8 kf1 = *reinterpret_cast<const bf16x8*>(Kbh + (s0 + 16 + lq) * DK + g * 8);

    // V/w A-fragments with labeling sigma: e<4 -> s0+4g+e, e>=4 -> s0+16+4g+e-4
    uint2 a0 = *reinterpret_cast<const uint2*>(Vbh + (lq)      * SEQ + s0 + 4 * g);
    uint2 b0 = *reinterpret_cast<const uint2*>(Vbh + (lq)      * SEQ + s0 + 16 + 4 * g);
    uint2 a1 = *reinterpret_cast<const uint2*>(Vbh + (16 + lq) * SEQ + s0 + 4 * g);
    uint2 b1 = *reinterpret_cast<const uint2*>(Vbh + (16 + lq) * SEQ + s0 + 16 + 4 * g);
    uint2 aw = *reinterpret_cast<const uint2*>(wb + s0 + 4 * g);
    uint2 bw = *reinterpret_cast<const uint2*>(wb + s0 + 16 + 4 * g);
    uint4 tv0 = {a0.x, a0.y, b0.x, b0.y};
    uint4 tv1 = {a1.x, a1.y, b1.x, b1.y};
    uint4 tw  = {aw.x, aw.y, bw.x, bw.y};
    bf16x8 vA0 = __builtin_bit_cast(bf16x8, tv0);
    bf16x8 vA1 = __builtin_bit_cast(bf16x8, tv1);
    bf16x8 wA  = __builtin_bit_cast(bf16x8, tw);

#pragma unroll
    for (int m = 0; m < 2; ++m) {
      f32x4 sc0 = mfma16(kf0, qf[m], zero4);  // P[s0+4g+r][q=16m+lq]
      f32x4 sc1 = mfma16(kf1, qf[m], zero4);  // P[s0+16+4g+r][q]
      uint4 t;
      t.x = pk2(__builtin_amdgcn_exp2f(sc0[0]), __builtin_amdgcn_exp2f(sc0[1]));
      t.y = pk2(__builtin_amdgcn_exp2f(sc0[2]), __builtin_amdgcn_exp2f(sc0[3]));
      t.z = pk2(__builtin_amdgcn_exp2f(sc1[0]), __builtin_amdgcn_exp2f(sc1[1]));
      t.w = pk2(__builtin_amdgcn_exp2f(sc1[2]), __builtin_amdgcn_exp2f(sc1[3]));
      bf16x8 pb = __builtin_bit_cast(bf16x8, t);  // B-fragment, q=lq, sigma order
      o[m][0] = mfma16(vA0, pb, o[m][0]);   // out[d=4g+r][q]
      o[m][1] = mfma16(vA1, pb, o[m][1]);   // out[d=16+4g+r][q]
      den[m]  = mfma16(wA,  pb, den[m]);    // all rows = den[q]
    }
  }

  // stash partials into ol[wid]: [q32][d], denominator in col 32
#pragma unroll
  for (int m = 0; m < 2; ++m) {
#pragma unroll
    for (int n = 0; n < 2; ++n)
#pragma unroll
      for (int r = 0; r < 4; ++r)
        ol[wid][16 * m + lq][16 * n + 4 * g + r] = o[m][n][r];
    if (g == 0) ol[wid][16 * m + lq][32] = den[m][0];
  }
  __syncthreads();

  const int b = bh >> 3, h = bh & 7;
  for (int idx = tid; idx < 32 * 32; idx += 256) {
    int q = idx >> 5, d = idx & 31;
    float num = ol[0][q][d] + ol[1][q][d] + ol[2][q][d] + ol[3][q][d];
    float dd  = ol[0][q][32] + ol[1][q][32] + ol[2][q][32] + ol[3][q][32];
    AOb[(b * SEQ + q0 + q) * D_MODEL + h * DK + d] = f2bf(num / dd);
  }
}

// ---------------- output projection GEMM (128x64 tiles, full CU coverage) ----
__global__ __launch_bounds__(256) void out_gemm(
    const unsigned short* __restrict__ Ab, const float* __restrict__ Wo,
    const float* __restrict__ bo, float* __restrict__ out) {
  __shared__ __align__(16) unsigned short As[128 * 72];
  __shared__ __align__(16) unsigned short Bs[64 * 72];
  const int tid = threadIdx.x, lane = tid & 63, wid = tid >> 6;
  const int bm = blockIdx.x * 128;
  const int ncol = blockIdx.y * 64;
  const int waveM = wid * 32;

  f32x4 acc[2][4] = {};
  for (int kt = 0; kt < 4; ++kt) {
    __syncthreads();
#pragma unroll
    for (int p = 0; p < 4; ++p) {
      int c = p * 256 + tid;
      int r = c >> 3, kc = c & 7;
      uint4 va = *reinterpret_cast<const uint4*>(Ab + (size_t)(bm + r) * 256 + kt * 64 + kc * 8);
      *reinterpret_cast<uint4*>(&As[r * 72 + kc * 8]) = va;
    }
#pragma unroll
    for (int p = 0; p < 2; ++p) {
      int c = p * 256 + tid;
      int r = c >> 3, kc = c & 7;
      const float* wp_ = Wo + (size_t)(ncol + r) * 256 + kt * 64 + kc * 8;
      float4 g0 = *reinterpret_cast<const float4*>(wp_);
      float4 g1 = *reinterpret_cast<const float4*>(wp_ + 4);
      ushort4 b0, b1;
      b0.x = f2bf(g0.x); b0.y = f2bf(g0.y); b0.z = f2bf(g0.z); b0.w = f2bf(g0.w);
      b1.x = f2bf(g1.x); b1.y = f2bf(g1.y); b1.z = f2bf(g1.z); b1.w = f2bf(g1.w);
      *reinterpret_cast<ushort4*>(&Bs[r * 72 + kc * 8])     = b0;
      *reinterpret_cast<ushort4*>(&Bs[r * 72 + kc * 8 + 4]) = b1;
    }
    __syncthreads();
#pragma unroll
    for (int ks = 0; ks < 2; ++ks) {
      bf16x8 af[2], bf[4];
#pragma unroll
      for (int m = 0; m < 2; ++m)
        af[m] = *reinterpret_cast<const bf16x8*>(&As[(waveM + m * 16 + (lane & 15)) * 72 + ks * 32 + (lane >> 4) * 8]);
#pragma unroll
      for (int n = 0; n < 4; ++n)
        bf[n] = *reinterpret_cast<const bf16x8*>(&Bs[(n * 16 + (lane & 15)) * 72 + ks * 32 + (lane >> 4) * 8]);
#pragma unroll
      for (int m = 0; m < 2; ++m)
#pragma unroll
        for (int n = 0; n < 4; ++n) acc[m][n] = mfma16(af[m], bf[n], acc[m][n]);
    }
  }
#pragma unroll
  for (int m = 0; m < 2; ++m)
#pragma unroll
    for (int n = 0; n < 4; ++n) {
      int j = ncol + n * 16 + (lane & 15);
      float bias_v = bo[j];
#pragma unroll
      for (int r = 0; r < 4; ++r) {
        int i = bm + waveM + m * 16 + (lane >> 4) * 4 + r;
        out[(size_t)i * D_MODEL + j] = acc[m][n][r] + bias_v;
      }
    }
}

// ---------------- launcher ----------------
extern "C" void kernel_launch(void* const* d_in, const int* in_sizes, int n_in,
                              void* d_out, int out_size, void* d_ws, size_t ws_size,
                              hipStream_t stream) {
  const float* x  = (const float*)d_in[0];
  const float* cx = (const float*)d_in[1];
  const float* Wq = (const float*)d_in[2];
  const float* bq = (const float*)d_in[3];
  const float* Wk = (const float*)d_in[4];
  const float* bk = (const float*)d_in[5];
  const float* Wv = (const float*)d_in[6];
  const float* bv = (const float*)d_in[7];
  const float* Wo = (const float*)d_in[8];
  const float* bo = (const float*)d_in[9];
  float* out = (float*)d_out;
  char* ws = (char*)d_ws;

  unsigned short* Qb  = (unsigned short*)(ws + (size_t)4  * 1024 * 1024);
  unsigned short* Kb  = (unsigned short*)(ws + (size_t)8  * 1024 * 1024);
  unsigned short* Vt  = (unsigned short*)(ws + (size_t)12 * 1024 * 1024);
  unsigned short* AOb = (unsigned short*)(ws + (size_t)16 * 1024 * 1024);
  unsigned short* wb  = (unsigned short*)(ws + (size_t)21 * 1024 * 1024);

  qkv_gemm<<<dim3(64, 12), 256, 0, stream>>>(x, cx, Wq, Wk, Wv, bq, bk, bv, Qb, Kb, Vt, wb);
  attn_kernel<<<2048, 256, 0, stream>>>(Qb, Kb, Vt, wb, AOb);
  out_gemm<<<dim3(64, 4), 256, 0, stream>>>(AOb, Wo, bo, out);
}

// Round 21
// 112.855 us; speedup vs baseline: 1.0043x; 1.0043x over previous
//
#include <hip/hip_runtime.h>
#include <hip/hip_bf16.h>
#include <stdint.h>

#define D_MODEL 256
#define NHEAD   8
#define DK      32
#define BATCH   4
#define SEQ     2048
#define MROWS   (BATCH*SEQ)   // 8192

typedef float  f32x4  __attribute__((ext_vector_type(4)));
typedef __bf16 bf16x8 __attribute__((ext_vector_type(8)));

__device__ __forceinline__ unsigned short f2bf(float f) {
  unsigned int u = __float_as_uint(f);
  unsigned int r = (u + 0x7FFFu + ((u >> 16) & 1u)) >> 16;
  return (unsigned short)r;
}
__device__ __forceinline__ float bfbits2f(unsigned short b) {
  return __uint_as_float(((unsigned int)b) << 16);
}

__device__ __forceinline__ f32x4 mfma16(bf16x8 a, bf16x8 b, f32x4 c) {
  return __builtin_amdgcn_mfma_f32_16x16x32_bf16(a, b, c, 0, 0, 0);
}
// packed f32->bf16 pair via the COMPILER-KNOWN intrinsic (emits
// v_cvt_pk_bf16_f32 with compiler-modeled hazards; RNE, same rounding as
// f2bf). Extracted with memcpy (bit_cast rejected: not trivially copyable).
__device__ __forceinline__ unsigned int pk2(float lo, float hi) {
  __hip_bfloat162 b2 = __float22bfloat162_rn(make_float2(lo, hi));
  unsigned int r;
  __builtin_memcpy(&r, &b2, sizeof(r));
  return r;
}

// scale folded into Wq/bq: (1/sqrt(32)) * log2(e)
#define QSCALE 0.2550599440097021f

// ---------------- fused QKV projection GEMM (128x64 tiles) -------------------
// y -> mat = y>>2 (0=Q,1=K,2=V), ncol=(y&3)*64. W casts fused into B staging;
// x cast fused into A staging. Q/K out: [bh][s][32]; V out: transposed +
// w-scaled: Vt[bh][d][s] = w_s*V[s][d]. y==0 blocks also materialize wb[].
__global__ __launch_bounds__(256) void qkv_gemm(
    const float* __restrict__ x, const float* __restrict__ cx,
    const float* __restrict__ Wq, const float* __restrict__ Wk,
    const float* __restrict__ Wv,
    const float* __restrict__ bq, const float* __restrict__ bk_, const float* __restrict__ bv,
    unsigned short* __restrict__ Qb, unsigned short* __restrict__ Kb,
    unsigned short* __restrict__ Vt, unsigned short* __restrict__ wb) {
  __shared__ __align__(16) unsigned short As[128 * 72];
  __shared__ __align__(16) unsigned short Bs[64 * 72];
  const int tid = threadIdx.x, lane = tid & 63, wid = tid >> 6;
  const int bm = blockIdx.x * 128;
  const int mat = blockIdx.y >> 2;
  const int ncol = (blockIdx.y & 3) * 64;
  const float* Wf = (mat == 0) ? Wq : ((mat == 1) ? Wk : Wv);
  const float* bias = (mat == 0) ? bq : ((mat == 1) ? bk_ : bv);
  const float bscale = (mat == 0) ? QSCALE : 1.0f;
  const int waveM = wid * 32;

  if (blockIdx.y == 0 && tid < 32) {
    int s = blockIdx.x * 32 + tid;
    wb[s] = (s == 0) ? (unsigned short)0 : f2bf(fabsf(cx[s] - cx[s - 1]));
  }

  f32x4 acc[2][4] = {};
  for (int kt = 0; kt < 4; ++kt) {
    __syncthreads();
#pragma unroll
    for (int p = 0; p < 4; ++p) {
      int c = p * 256 + tid;
      int r = c >> 3, kc = c & 7;
      const float* xp = x + (size_t)(bm + r) * 256 + kt * 64 + kc * 8;
      float4 f0 = *reinterpret_cast<const float4*>(xp);
      float4 f1 = *reinterpret_cast<const float4*>(xp + 4);
      ushort4 h0, h1;
      h0.x = f2bf(f0.x); h0.y = f2bf(f0.y); h0.z = f2bf(f0.z); h0.w = f2bf(f0.w);
      h1.x = f2bf(f1.x); h1.y = f2bf(f1.y); h1.z = f2bf(f1.z); h1.w = f2bf(f1.w);
      *reinterpret_cast<ushort4*>(&As[r * 72 + kc * 8])     = h0;
      *reinterpret_cast<ushort4*>(&As[r * 72 + kc * 8 + 4]) = h1;
    }
#pragma unroll
    for (int p = 0; p < 2; ++p) {
      int c = p * 256 + tid;
      int r = c >> 3, kc = c & 7;
      const float* wp_ = Wf + (size_t)(ncol + r) * 256 + kt * 64 + kc * 8;
      float4 g0 = *reinterpret_cast<const float4*>(wp_);
      float4 g1 = *reinterpret_cast<const float4*>(wp_ + 4);
      ushort4 b0, b1;
      b0.x = f2bf(g0.x * bscale); b0.y = f2bf(g0.y * bscale);
      b0.z = f2bf(g0.z * bscale); b0.w = f2bf(g0.w * bscale);
      b1.x = f2bf(g1.x * bscale); b1.y = f2bf(g1.y * bscale);
      b1.z = f2bf(g1.z * bscale); b1.w = f2bf(g1.w * bscale);
      *reinterpret_cast<ushort4*>(&Bs[r * 72 + kc * 8])     = b0;
      *reinterpret_cast<ushort4*>(&Bs[r * 72 + kc * 8 + 4]) = b1;
    }
    __syncthreads();
#pragma unroll
    for (int ks = 0; ks < 2; ++ks) {
      bf16x8 af[2], bf[4];
#pragma unroll
      for (int m = 0; m < 2; ++m)
        af[m] = *reinterpret_cast<const bf16x8*>(&As[(waveM + m * 16 + (lane & 15)) * 72 + ks * 32 + (lane >> 4) * 8]);
#pragma unroll
      for (int n = 0; n < 4; ++n)
        bf[n] = *reinterpret_cast<const bf16x8*>(&Bs[(n * 16 + (lane & 15)) * 72 + ks * 32 + (lane >> 4) * 8]);
#pragma unroll
      for (int m = 0; m < 2; ++m)
#pragma unroll
        for (int n = 0; n < 4; ++n) acc[m][n] = mfma16(af[m], bf[n], acc[m][n]);
    }
  }
#pragma unroll
  for (int m = 0; m < 2; ++m) {
    int i0 = bm + waveM + m * 16 + (lane >> 4) * 4;  // row of r=0 (mult of 4)
    int b = i0 >> 11, s = i0 & 2047;
    float wv4[4] = {0.f, 0.f, 0.f, 0.f};
    if (mat == 2) {
      float cm = (s > 0) ? cx[s - 1] : 0.0f;
      float c0 = cx[s], c1 = cx[s + 1], c2 = cx[s + 2], c3 = cx[s + 3];
      wv4[0] = (s > 0) ? bfbits2f(f2bf(fabsf(c0 - cm))) : 0.0f;
      wv4[1] = bfbits2f(f2bf(fabsf(c1 - c0)));
      wv4[2] = bfbits2f(f2bf(fabsf(c2 - c1)));
      wv4[3] = bfbits2f(f2bf(fabsf(c3 - c2)));
    }
#pragma unroll
    for (int n = 0; n < 4; ++n) {
      int j = ncol + n * 16 + (lane & 15);
      float bias_v = bias[j] * bscale;
      int h = j >> 5, d = j & 31;
      if (mat == 2) {
        ushort4 pk;
        pk.x = f2bf((acc[m][n][0] + bias_v) * wv4[0]);
        pk.y = f2bf((acc[m][n][1] + bias_v) * wv4[1]);
        pk.z = f2bf((acc[m][n][2] + bias_v) * wv4[2]);
        pk.w = f2bf((acc[m][n][3] + bias_v) * wv4[3]);
        *reinterpret_cast<ushort4*>(&Vt[((b * NHEAD + h) * DK + d) * SEQ + s]) = pk;
      } else {
        unsigned short* dst = (mat == 0) ? Qb : Kb;
#pragma unroll
        for (int r = 0; r < 4; ++r)
          dst[((b * NHEAD + h) * SEQ + s + r) * DK + d] = f2bf(acc[m][n][r] + bias_v);
      }
    }
  }
}

// ---------------- fused weighted attention (P consumed in situ as B operand) -
// r20-PROVEN register path (passed, absmax 6.1e-5): lane (g,lq) packs its own
// scores sc0/sc1 in order -> PV B-fragment for q=lq with labeling sigma;
// V/w loaded as A-operands with the same labeling. NO LDS P transport.
// ONE change vs r20: packing via compiler-known __float22bfloat162_rn
// (single v_cvt_pk_bf16_f32, hazards modeled) instead of ~28 integer VALU ops
// on the critical QK->exp->pack->PV chain (r20's 87.5us regression cause).
// XCD-affinity grid kept (FETCH 34.8->6.2MB, K/V L2-resident).
__global__ __launch_bounds__(256, 4) void attn_kernel(
    const unsigned short* __restrict__ Qb, const unsigned short* __restrict__ Kb,
    const unsigned short* __restrict__ Vt, const unsigned short* __restrict__ wb,
    unsigned short* __restrict__ AOb) {
  __shared__ float ol[4][32][36];
  const int tid = threadIdx.x, lane = tid & 63, wid = tid >> 6;
  const int g = lane >> 4, lq = lane & 15;

  // XCD-affinity decode: xcd = bid%8 serves bh in [4*xcd, 4*xcd+4)
  const int bid = blockIdx.x;
  const int xcd = bid & 7, slot = bid >> 3;        // 256 slots per XCD
  const int bh = xcd * 4 + (slot >> 6);
  const int q0 = (slot & 63) * 32;

  const unsigned short* Qbh = Qb + bh * SEQ * DK;
  const unsigned short* Kbh = Kb + bh * SEQ * DK;
  const unsigned short* Vbh = Vt + bh * DK * SEQ;

  bf16x8 qf[2];
  qf[0] = *reinterpret_cast<const bf16x8*>(Qbh + (q0 + lq) * DK + g * 8);
  qf[1] = *reinterpret_cast<const bf16x8*>(Qbh + (q0 + 16 + lq) * DK + g * 8);

  f32x4 o[2][2] = {};   // [q-tile m][d-tile n]; lane: out[d=16n+4g+r][q=16m+lq]
  f32x4 den[2] = {};
  const f32x4 zero4 = {0.f, 0.f, 0.f, 0.f};
  const int sbase = wid * (SEQ / 4);

#pragma unroll 2
  for (int st = 0; st < (SEQ / 4) / 32; ++st) {
    const int s0 = sbase + st * 32;
    bf16x8 kf0 = *reinterpret_cast<const bf16x8*>(Kbh + (s0 + lq) * DK + g * 8);
    bf16x8 kf1 = *reinterpret_cast<const bf16x8*>(Kbh + (s0 + 16 + lq) * DK + g * 8);

    // V/w A-fragments with labeling sigma: e<4 -> s0+4g+e, e>=4 -> s0+16+4g+e-4
    uint2 a0 = *reinterpret_cast<const uint2*>(Vbh + (lq)      * SEQ + s0 + 4 * g);
    uint2 b0 = *reinterpret_cast<const uint2*>(Vbh + (lq)      * SEQ + s0 + 16 + 4 * g);
    uint2 a1 = *reinterpret_cast<const uint2*>(Vbh + (16 + lq) * SEQ + s0 + 4 * g);
    uint2 b1 = *reinterpret_cast<const uint2*>(Vbh + (16 + lq) * SEQ + s0 + 16 + 4 * g);
    uint2 aw = *reinterpret_cast<const uint2*>(wb + s0 + 4 * g);
    uint2 bw = *reinterpret_cast<const uint2*>(wb + s0 + 16 + 4 * g);
    uint4 tv0 = {a0.x, a0.y, b0.x, b0.y};
    uint4 tv1 = {a1.x, a1.y, b1.x, b1.y};
    uint4 tw  = {aw.x, aw.y, bw.x, bw.y};
    bf16x8 vA0 = __builtin_bit_cast(bf16x8, tv0);
    bf16x8 vA1 = __builtin_bit_cast(bf16x8, tv1);
    bf16x8 wA  = __builtin_bit_cast(bf16x8, tw);

#pragma unroll
    for (int m = 0; m < 2; ++m) {
      f32x4 sc0 = mfma16(kf0, qf[m], zero4);  // P[s0+4g+r][q=16m+lq]
      f32x4 sc1 = mfma16(kf1, qf[m], zero4);  // P[s0+16+4g+r][q]
      uint4 t;
      t.x = pk2(__builtin_amdgcn_exp2f(sc0[0]), __builtin_amdgcn_exp2f(sc0[1]));
      t.y = pk2(__builtin_amdgcn_exp2f(sc0[2]), __builtin_amdgcn_exp2f(sc0[3]));
      t.z = pk2(__builtin_amdgcn_exp2f(sc1[0]), __builtin_amdgcn_exp2f(sc1[1]));
      t.w = pk2(__builtin_amdgcn_exp2f(sc1[2]), __builtin_amdgcn_exp2f(sc1[3]));
      bf16x8 pb = __builtin_bit_cast(bf16x8, t);  // B-fragment, q=lq, sigma order
      o[m][0] = mfma16(vA0, pb, o[m][0]);   // out[d=4g+r][q]
      o[m][1] = mfma16(vA1, pb, o[m][1]);   // out[d=16+4g+r][q]
      den[m]  = mfma16(wA,  pb, den[m]);    // all rows = den[q]
    }
  }

  // stash partials into ol[wid]: [q32][d], denominator in col 32
#pragma unroll
  for (int m = 0; m < 2; ++m) {
#pragma unroll
    for (int n = 0; n < 2; ++n)
#pragma unroll
      for (int r = 0; r < 4; ++r)
        ol[wid][16 * m + lq][16 * n + 4 * g + r] = o[m][n][r];
    if (g == 0) ol[wid][16 * m + lq][32] = den[m][0];
  }
  __syncthreads();

  const int b = bh >> 3, h = bh & 7;
  for (int idx = tid; idx < 32 * 32; idx += 256) {
    int q = idx >> 5, d = idx & 31;
    float num = ol[0][q][d] + ol[1][q][d] + ol[2][q][d] + ol[3][q][d];
    float dd  = ol[0][q][32] + ol[1][q][32] + ol[2][q][32] + ol[3][q][32];
    AOb[(b * SEQ + q0 + q) * D_MODEL + h * DK + d] = f2bf(num / dd);
  }
}

// ---------------- output projection GEMM (128x64 tiles, full CU coverage) ----
__global__ __launch_bounds__(256) void out_gemm(
    const unsigned short* __restrict__ Ab, const float* __restrict__ Wo,
    const float* __restrict__ bo, float* __restrict__ out) {
  __shared__ __align__(16) unsigned short As[128 * 72];
  __shared__ __align__(16) unsigned short Bs[64 * 72];
  const int tid = threadIdx.x, lane = tid & 63, wid = tid >> 6;
  const int bm = blockIdx.x * 128;
  const int ncol = blockIdx.y * 64;
  const int waveM = wid * 32;

  f32x4 acc[2][4] = {};
  for (int kt = 0; kt < 4; ++kt) {
    __syncthreads();
#pragma unroll
    for (int p = 0; p < 4; ++p) {
      int c = p * 256 + tid;
      int r = c >> 3, kc = c & 7;
      uint4 va = *reinterpret_cast<const uint4*>(Ab + (size_t)(bm + r) * 256 + kt * 64 + kc * 8);
      *reinterpret_cast<uint4*>(&As[r * 72 + kc * 8]) = va;
    }
#pragma unroll
    for (int p = 0; p < 2; ++p) {
      int c = p * 256 + tid;
      int r = c >> 3, kc = c & 7;
      const float* wp_ = Wo + (size_t)(ncol + r) * 256 + kt * 64 + kc * 8;
      float4 g0 = *reinterpret_cast<const float4*>(wp_);
      float4 g1 = *reinterpret_cast<const float4*>(wp_ + 4);
      ushort4 b0, b1;
      b0.x = f2bf(g0.x); b0.y = f2bf(g0.y); b0.z = f2bf(g0.z); b0.w = f2bf(g0.w);
      b1.x = f2bf(g1.x); b1.y = f2bf(g1.y); b1.z = f2bf(g1.z); b1.w = f2bf(g1.w);
      *reinterpret_cast<ushort4*>(&Bs[r * 72 + kc * 8])     = b0;
      *reinterpret_cast<ushort4*>(&Bs[r * 72 + kc * 8 + 4]) = b1;
    }
    __syncthreads();
#pragma unroll
    for (int ks = 0; ks < 2; ++ks) {
      bf16x8 af[2], bf[4];
#pragma unroll
      for (int m = 0; m < 2; ++m)
        af[m] = *reinterpret_cast<const bf16x8*>(&As[(waveM + m * 16 + (lane & 15)) * 72 + ks * 32 + (lane >> 4) * 8]);
#pragma unroll
      for (int n = 0; n < 4; ++n)
        bf[n] = *reinterpret_cast<const bf16x8*>(&Bs[(n * 16 + (lane & 15)) * 72 + ks * 32 + (lane >> 4) * 8]);
#pragma unroll
      for (int m = 0; m < 2; ++m)
#pragma unroll
        for (int n = 0; n < 4; ++n) acc[m][n] = mfma16(af[m], bf[n], acc[m][n]);
    }
  }
#pragma unroll
  for (int m = 0; m < 2; ++m)
#pragma unroll
    for (int n = 0; n < 4; ++n) {
      int j = ncol + n * 16 + (lane & 15);
      float bias_v = bo[j];
#pragma unroll
      for (int r = 0; r < 4; ++r) {
        int i = bm + waveM + m * 16 + (lane >> 4) * 4 + r;
        out[(size_t)i * D_MODEL + j] = acc[m][n][r] + bias_v;
      }
    }
}

// ---------------- launcher ----------------
extern "C" void kernel_launch(void* const* d_in, const int* in_sizes, int n_in,
                              void* d_out, int out_size, void* d_ws, size_t ws_size,
                              hipStream_t stream) {
  const float* x  = (const float*)d_in[0];
  const float* cx = (const float*)d_in[1];
  const float* Wq = (const float*)d_in[2];
  const float* bq = (const float*)d_in[3];
  const float* Wk = (const float*)d_in[4];
  const float* bk = (const float*)d_in[5];
  const float* Wv = (const float*)d_in[6];
  const float* bv = (const float*)d_in[7];
  const float* Wo = (const float*)d_in[8];
  const float* bo = (const float*)d_in[9];
  float* out = (float*)d_out;
  char* ws = (char*)d_ws;

  unsigned short* Qb  = (unsigned short*)(ws + (size_t)4  * 1024 * 1024);
  unsigned short* Kb  = (unsigned short*)(ws + (size_t)8  * 1024 * 1024);
  unsigned short* Vt  = (unsigned short*)(ws + (size_t)12 * 1024 * 1024);
  unsigned short* AOb = (unsigned short*)(ws + (size_t)16 * 1024 * 1024);
  unsigned short* wb  = (unsigned short*)(ws + (size_t)21 * 1024 * 1024);

  qkv_gemm<<<dim3(64, 12), 256, 0, stream>>>(x, cx, Wq, Wk, Wv, bq, bk, bv, Qb, Kb, Vt, wb);
  attn_kernel<<<2048, 256, 0, stream>>>(Qb, Kb, Vt, wb, AOb);
  out_gemm<<<dim3(64, 4), 256, 0, stream>>>(AOb, Wo, bo, out);
}

// Round 22
// 112.598 us; speedup vs baseline: 1.0066x; 1.0023x over previous
//
#include <hip/hip_runtime.h>
#include <hip/hip_bf16.h>
#include <stdint.h>

#define D_MODEL 256
#define NHEAD   8
#define DK      32
#define BATCH   4
#define SEQ     2048
#define MROWS   (BATCH*SEQ)   // 8192

typedef float  f32x4  __attribute__((ext_vector_type(4)));
typedef __bf16 bf16x8 __attribute__((ext_vector_type(8)));

__device__ __forceinline__ unsigned short f2bf(float f) {
  unsigned int u = __float_as_uint(f);
  unsigned int r = (u + 0x7FFFu + ((u >> 16) & 1u)) >> 16;
  return (unsigned short)r;
}
__device__ __forceinline__ float bfbits2f(unsigned short b) {
  return __uint_as_float(((unsigned int)b) << 16);
}

__device__ __forceinline__ f32x4 mfma16(bf16x8 a, bf16x8 b, f32x4 c) {
  return __builtin_amdgcn_mfma_f32_16x16x32_bf16(a, b, c, 0, 0, 0);
}
// packed f32->bf16 pair via the compiler-known intrinsic (v_cvt_pk_bf16_f32,
// hazards modeled; RNE, same rounding as f2bf).
__device__ __forceinline__ unsigned int pk2(float lo, float hi) {
  __hip_bfloat162 b2 = __float22bfloat162_rn(make_float2(lo, hi));
  unsigned int r;
  __builtin_memcpy(&r, &b2, sizeof(r));
  return r;
}
// exp+pack a score pair (sc0: s=4g+r, sc1: s=16+4g+r) -> B-fragment (sigma order)
__device__ __forceinline__ bf16x8 exppack(f32x4 sc0, f32x4 sc1) {
  uint4 t;
  t.x = pk2(__builtin_amdgcn_exp2f(sc0[0]), __builtin_amdgcn_exp2f(sc0[1]));
  t.y = pk2(__builtin_amdgcn_exp2f(sc0[2]), __builtin_amdgcn_exp2f(sc0[3]));
  t.z = pk2(__builtin_amdgcn_exp2f(sc1[0]), __builtin_amdgcn_exp2f(sc1[1]));
  t.w = pk2(__builtin_amdgcn_exp2f(sc1[2]), __builtin_amdgcn_exp2f(sc1[3]));
  return __builtin_bit_cast(bf16x8, t);
}

// scale folded into Wq/bq: (1/sqrt(32)) * log2(e)
#define QSCALE 0.2550599440097021f

// ---------------- fused QKV projection GEMM (128x64 tiles) -------------------
// y -> mat = y>>2 (0=Q,1=K,2=V), ncol=(y&3)*64. W casts fused into B staging;
// x cast fused into A staging. Q/K out: [bh][s][32]; V out: transposed +
// w-scaled: Vt[bh][d][s] = w_s*V[s][d]. y==0 blocks also materialize wb[].
__global__ __launch_bounds__(256) void qkv_gemm(
    const float* __restrict__ x, const float* __restrict__ cx,
    const float* __restrict__ Wq, const float* __restrict__ Wk,
    const float* __restrict__ Wv,
    const float* __restrict__ bq, const float* __restrict__ bk_, const float* __restrict__ bv,
    unsigned short* __restrict__ Qb, unsigned short* __restrict__ Kb,
    unsigned short* __restrict__ Vt, unsigned short* __restrict__ wb) {
  __shared__ __align__(16) unsigned short As[128 * 72];
  __shared__ __align__(16) unsigned short Bs[64 * 72];
  const int tid = threadIdx.x, lane = tid & 63, wid = tid >> 6;
  const int bm = blockIdx.x * 128;
  const int mat = blockIdx.y >> 2;
  const int ncol = (blockIdx.y & 3) * 64;
  const float* Wf = (mat == 0) ? Wq : ((mat == 1) ? Wk : Wv);
  const float* bias = (mat == 0) ? bq : ((mat == 1) ? bk_ : bv);
  const float bscale = (mat == 0) ? QSCALE : 1.0f;
  const int waveM = wid * 32;

  if (blockIdx.y == 0 && tid < 32) {
    int s = blockIdx.x * 32 + tid;
    wb[s] = (s == 0) ? (unsigned short)0 : f2bf(fabsf(cx[s] - cx[s - 1]));
  }

  f32x4 acc[2][4] = {};
  for (int kt = 0; kt < 4; ++kt) {
    __syncthreads();
#pragma unroll
    for (int p = 0; p < 4; ++p) {
      int c = p * 256 + tid;
      int r = c >> 3, kc = c & 7;
      const float* xp = x + (size_t)(bm + r) * 256 + kt * 64 + kc * 8;
      float4 f0 = *reinterpret_cast<const float4*>(xp);
      float4 f1 = *reinterpret_cast<const float4*>(xp + 4);
      ushort4 h0, h1;
      h0.x = f2bf(f0.x); h0.y = f2bf(f0.y); h0.z = f2bf(f0.z); h0.w = f2bf(f0.w);
      h1.x = f2bf(f1.x); h1.y = f2bf(f1.y); h1.z = f2bf(f1.z); h1.w = f2bf(f1.w);
      *reinterpret_cast<ushort4*>(&As[r * 72 + kc * 8])     = h0;
      *reinterpret_cast<ushort4*>(&As[r * 72 + kc * 8 + 4]) = h1;
    }
#pragma unroll
    for (int p = 0; p < 2; ++p) {
      int c = p * 256 + tid;
      int r = c >> 3, kc = c & 7;
      const float* wp_ = Wf + (size_t)(ncol + r) * 256 + kt * 64 + kc * 8;
      float4 g0 = *reinterpret_cast<const float4*>(wp_);
      float4 g1 = *reinterpret_cast<const float4*>(wp_ + 4);
      ushort4 b0, b1;
      b0.x = f2bf(g0.x * bscale); b0.y = f2bf(g0.y * bscale);
      b0.z = f2bf(g0.z * bscale); b0.w = f2bf(g0.w * bscale);
      b1.x = f2bf(g1.x * bscale); b1.y = f2bf(g1.y * bscale);
      b1.z = f2bf(g1.z * bscale); b1.w = f2bf(g1.w * bscale);
      *reinterpret_cast<ushort4*>(&Bs[r * 72 + kc * 8])     = b0;
      *reinterpret_cast<ushort4*>(&Bs[r * 72 + kc * 8 + 4]) = b1;
    }
    __syncthreads();
#pragma unroll
    for (int ks = 0; ks < 2; ++ks) {
      bf16x8 af[2], bf[4];
#pragma unroll
      for (int m = 0; m < 2; ++m)
        af[m] = *reinterpret_cast<const bf16x8*>(&As[(waveM + m * 16 + (lane & 15)) * 72 + ks * 32 + (lane >> 4) * 8]);
#pragma unroll
      for (int n = 0; n < 4; ++n)
        bf[n] = *reinterpret_cast<const bf16x8*>(&Bs[(n * 16 + (lane & 15)) * 72 + ks * 32 + (lane >> 4) * 8]);
#pragma unroll
      for (int m = 0; m < 2; ++m)
#pragma unroll
        for (int n = 0; n < 4; ++n) acc[m][n] = mfma16(af[m], bf[n], acc[m][n]);
    }
  }
#pragma unroll
  for (int m = 0; m < 2; ++m) {
    int i0 = bm + waveM + m * 16 + (lane >> 4) * 4;  // row of r=0 (mult of 4)
    int b = i0 >> 11, s = i0 & 2047;
    float wv4[4] = {0.f, 0.f, 0.f, 0.f};
    if (mat == 2) {
      float cm = (s > 0) ? cx[s - 1] : 0.0f;
      float c0 = cx[s], c1 = cx[s + 1], c2 = cx[s + 2], c3 = cx[s + 3];
      wv4[0] = (s > 0) ? bfbits2f(f2bf(fabsf(c0 - cm))) : 0.0f;
      wv4[1] = bfbits2f(f2bf(fabsf(c1 - c0)));
      wv4[2] = bfbits2f(f2bf(fabsf(c2 - c1)));
      wv4[3] = bfbits2f(f2bf(fabsf(c3 - c2)));
    }
#pragma unroll
    for (int n = 0; n < 4; ++n) {
      int j = ncol + n * 16 + (lane & 15);
      float bias_v = bias[j] * bscale;
      int h = j >> 5, d = j & 31;
      if (mat == 2) {
        ushort4 pk;
        pk.x = f2bf((acc[m][n][0] + bias_v) * wv4[0]);
        pk.y = f2bf((acc[m][n][1] + bias_v) * wv4[1]);
        pk.z = f2bf((acc[m][n][2] + bias_v) * wv4[2]);
        pk.w = f2bf((acc[m][n][3] + bias_v) * wv4[3]);
        *reinterpret_cast<ushort4*>(&Vt[((b * NHEAD + h) * DK + d) * SEQ + s]) = pk;
      } else {
        unsigned short* dst = (mat == 0) ? Qb : Kb;
#pragma unroll
        for (int r = 0; r < 4; ++r)
          dst[((b * NHEAD + h) * SEQ + s + r) * DK + d] = f2bf(acc[m][n][r] + bias_v);
      }
    }
  }
}

// ---------------- fused weighted attention (register path + 1-step skew) -----
// r20/r21-PROVEN in-situ-B register path (absmax 6.1e-5, no LDS P transport),
// SOFTWARE-SKEWED: per iteration issue QK MFMAs for st+1 FIRST, then PV MFMAs
// for st (consuming pbA/pbB packed LAST iteration — independent of the QK just
// issued), then exp/pack st+1 on the VALU pipe while PV executes on the MFMA
// pipe. Pure SSA reordering — no memory hazards (r13's LDS-skew failure mode
// does not exist here), identical arithmetic & accumulation order to r21.
// XCD-affinity grid kept (FETCH 6.2MB, K/V L2-resident).
__global__ __launch_bounds__(256, 4) void attn_kernel(
    const unsigned short* __restrict__ Qb, const unsigned short* __restrict__ Kb,
    const unsigned short* __restrict__ Vt, const unsigned short* __restrict__ wb,
    unsigned short* __restrict__ AOb) {
  __shared__ float ol[4][32][36];
  const int tid = threadIdx.x, lane = tid & 63, wid = tid >> 6;
  const int g = lane >> 4, lq = lane & 15;

  // XCD-affinity decode: xcd = bid%8 serves bh in [4*xcd, 4*xcd+4)
  const int bid = blockIdx.x;
  const int xcd = bid & 7, slot = bid >> 3;        // 256 slots per XCD
  const int bh = xcd * 4 + (slot >> 6);
  const int q0 = (slot & 63) * 32;

  const unsigned short* Qbh = Qb + bh * SEQ * DK;
  const unsigned short* Kbh = Kb + bh * SEQ * DK;
  const unsigned short* Vbh = Vt + bh * DK * SEQ;

  bf16x8 qf0 = *reinterpret_cast<const bf16x8*>(Qbh + (q0 + lq) * DK + g * 8);
  bf16x8 qf1 = *reinterpret_cast<const bf16x8*>(Qbh + (q0 + 16 + lq) * DK + g * 8);

  f32x4 o[2][2] = {};   // [q-tile m][d-tile n]; lane: out[d=16n+4g+r][q=16m+lq]
  f32x4 den[2] = {};
  const f32x4 zero4 = {0.f, 0.f, 0.f, 0.f};
  const int sbase = wid * (SEQ / 4);

  // prologue: QK + exp/pack for st=0
  bf16x8 pbA, pbB;
  {
    bf16x8 k0 = *reinterpret_cast<const bf16x8*>(Kbh + (sbase + lq) * DK + g * 8);
    bf16x8 k1 = *reinterpret_cast<const bf16x8*>(Kbh + (sbase + 16 + lq) * DK + g * 8);
    f32x4 sA0 = mfma16(k0, qf0, zero4);
    f32x4 sA1 = mfma16(k1, qf0, zero4);
    f32x4 sB0 = mfma16(k0, qf1, zero4);
    f32x4 sB1 = mfma16(k1, qf1, zero4);
    pbA = exppack(sA0, sA1);
    pbB = exppack(sB0, sB1);
  }

  for (int st = 0; st < 15; ++st) {
    const int s0 = sbase + st * 32;
    const int s1 = s0 + 32;
    // V/w A-fragments for st (labeling sigma)
    uint2 a0 = *reinterpret_cast<const uint2*>(Vbh + (lq)      * SEQ + s0 + 4 * g);
    uint2 b0 = *reinterpret_cast<const uint2*>(Vbh + (lq)      * SEQ + s0 + 16 + 4 * g);
    uint2 a1 = *reinterpret_cast<const uint2*>(Vbh + (16 + lq) * SEQ + s0 + 4 * g);
    uint2 b1 = *reinterpret_cast<const uint2*>(Vbh + (16 + lq) * SEQ + s0 + 16 + 4 * g);
    uint2 aw = *reinterpret_cast<const uint2*>(wb + s0 + 4 * g);
    uint2 bw = *reinterpret_cast<const uint2*>(wb + s0 + 16 + 4 * g);
    uint4 tv0 = {a0.x, a0.y, b0.x, b0.y};
    uint4 tv1 = {a1.x, a1.y, b1.x, b1.y};
    uint4 tw  = {aw.x, aw.y, bw.x, bw.y};
    bf16x8 vA0 = __builtin_bit_cast(bf16x8, tv0);
    bf16x8 vA1 = __builtin_bit_cast(bf16x8, tv1);
    bf16x8 wA  = __builtin_bit_cast(bf16x8, tw);

    // issue QK MFMAs for st+1 (results consumed after PV below)
    bf16x8 k0 = *reinterpret_cast<const bf16x8*>(Kbh + (s1 + lq) * DK + g * 8);
    bf16x8 k1 = *reinterpret_cast<const bf16x8*>(Kbh + (s1 + 16 + lq) * DK + g * 8);
    f32x4 nA0 = mfma16(k0, qf0, zero4);
    f32x4 nA1 = mfma16(k1, qf0, zero4);
    f32x4 nB0 = mfma16(k0, qf1, zero4);
    f32x4 nB1 = mfma16(k1, qf1, zero4);

    // PV for st (independent of the QK just issued)
    o[0][0] = mfma16(vA0, pbA, o[0][0]);
    o[0][1] = mfma16(vA1, pbA, o[0][1]);
    den[0]  = mfma16(wA,  pbA, den[0]);
    o[1][0] = mfma16(vA0, pbB, o[1][0]);
    o[1][1] = mfma16(vA1, pbB, o[1][1]);
    den[1]  = mfma16(wA,  pbB, den[1]);

    // exp/pack st+1 (VALU; overlaps PV on the MFMA pipe)
    pbA = exppack(nA0, nA1);
    pbB = exppack(nB0, nB1);
  }

  // epilogue: PV for st=15
  {
    const int s0 = sbase + 15 * 32;
    uint2 a0 = *reinterpret_cast<const uint2*>(Vbh + (lq)      * SEQ + s0 + 4 * g);
    uint2 b0 = *reinterpret_cast<const uint2*>(Vbh + (lq)      * SEQ + s0 + 16 + 4 * g);
    uint2 a1 = *reinterpret_cast<const uint2*>(Vbh + (16 + lq) * SEQ + s0 + 4 * g);
    uint2 b1 = *reinterpret_cast<const uint2*>(Vbh + (16 + lq) * SEQ + s0 + 16 + 4 * g);
    uint2 aw = *reinterpret_cast<const uint2*>(wb + s0 + 4 * g);
    uint2 bw = *reinterpret_cast<const uint2*>(wb + s0 + 16 + 4 * g);
    uint4 tv0 = {a0.x, a0.y, b0.x, b0.y};
    uint4 tv1 = {a1.x, a1.y, b1.x, b1.y};
    uint4 tw  = {aw.x, aw.y, bw.x, bw.y};
    bf16x8 vA0 = __builtin_bit_cast(bf16x8, tv0);
    bf16x8 vA1 = __builtin_bit_cast(bf16x8, tv1);
    bf16x8 wA  = __builtin_bit_cast(bf16x8, tw);
    o[0][0] = mfma16(vA0, pbA, o[0][0]);
    o[0][1] = mfma16(vA1, pbA, o[0][1]);
    den[0]  = mfma16(wA,  pbA, den[0]);
    o[1][0] = mfma16(vA0, pbB, o[1][0]);
    o[1][1] = mfma16(vA1, pbB, o[1][1]);
    den[1]  = mfma16(wA,  pbB, den[1]);
  }

  // stash partials into ol[wid]: [q32][d], denominator in col 32
#pragma unroll
  for (int m = 0; m < 2; ++m) {
#pragma unroll
    for (int n = 0; n < 2; ++n)
#pragma unroll
      for (int r = 0; r < 4; ++r)
        ol[wid][16 * m + lq][16 * n + 4 * g + r] = o[m][n][r];
    if (g == 0) ol[wid][16 * m + lq][32] = den[m][0];
  }
  __syncthreads();

  const int b = bh >> 3, h = bh & 7;
  for (int idx = tid; idx < 32 * 32; idx += 256) {
    int q = idx >> 5, d = idx & 31;
    float num = ol[0][q][d] + ol[1][q][d] + ol[2][q][d] + ol[3][q][d];
    float dd  = ol[0][q][32] + ol[1][q][32] + ol[2][q][32] + ol[3][q][32];
    AOb[(b * SEQ + q0 + q) * D_MODEL + h * DK + d] = f2bf(num / dd);
  }
}

// ---------------- output projection GEMM (128x64 tiles, full CU coverage) ----
__global__ __launch_bounds__(256) void out_gemm(
    const unsigned short* __restrict__ Ab, const float* __restrict__ Wo,
    const float* __restrict__ bo, float* __restrict__ out) {
  __shared__ __align__(16) unsigned short As[128 * 72];
  __shared__ __align__(16) unsigned short Bs[64 * 72];
  const int tid = threadIdx.x, lane = tid & 63, wid = tid >> 6;
  const int bm = blockIdx.x * 128;
  const int ncol = blockIdx.y * 64;
  const int waveM = wid * 32;

  f32x4 acc[2][4] = {};
  for (int kt = 0; kt < 4; ++kt) {
    __syncthreads();
#pragma unroll
    for (int p = 0; p < 4; ++p) {
      int c = p * 256 + tid;
      int r = c >> 3, kc = c & 7;
      uint4 va = *reinterpret_cast<const uint4*>(Ab + (size_t)(bm + r) * 256 + kt * 64 + kc * 8);
      *reinterpret_cast<uint4*>(&As[r * 72 + kc * 8]) = va;
    }
#pragma unroll
    for (int p = 0; p < 2; ++p) {
      int c = p * 256 + tid;
      int r = c >> 3, kc = c & 7;
      const float* wp_ = Wo + (size_t)(ncol + r) * 256 + kt * 64 + kc * 8;
      float4 g0 = *reinterpret_cast<const float4*>(wp_);
      float4 g1 = *reinterpret_cast<const float4*>(wp_ + 4);
      ushort4 b0, b1;
      b0.x = f2bf(g0.x); b0.y = f2bf(g0.y); b0.z = f2bf(g0.z); b0.w = f2bf(g0.w);
      b1.x = f2bf(g1.x); b1.y = f2bf(g1.y); b1.z = f2bf(g1.z); b1.w = f2bf(g1.w);
      *reinterpret_cast<ushort4*>(&Bs[r * 72 + kc * 8])     = b0;
      *reinterpret_cast<ushort4*>(&Bs[r * 72 + kc * 8 + 4]) = b1;
    }
    __syncthreads();
#pragma unroll
    for (int ks = 0; ks < 2; ++ks) {
      bf16x8 af[2], bf[4];
#pragma unroll
      for (int m = 0; m < 2; ++m)
        af[m] = *reinterpret_cast<const bf16x8*>(&As[(waveM + m * 16 + (lane & 15)) * 72 + ks * 32 + (lane >> 4) * 8]);
#pragma unroll
      for (int n = 0; n < 4; ++n)
        bf[n] = *reinterpret_cast<const bf16x8*>(&Bs[(n * 16 + (lane & 15)) * 72 + ks * 32 + (lane >> 4) * 8]);
#pragma unroll
      for (int m = 0; m < 2; ++m)
#pragma unroll
        for (int n = 0; n < 4; ++n) acc[m][n] = mfma16(af[m], bf[n], acc[m][n]);
    }
  }
#pragma unroll
  for (int m = 0; m < 2; ++m)
#pragma unroll
    for (int n = 0; n < 4; ++n) {
      int j = ncol + n * 16 + (lane & 15);
      float bias_v = bo[j];
#pragma unroll
      for (int r = 0; r < 4; ++r) {
        int i = bm + waveM + m * 16 + (lane >> 4) * 4 + r;
        out[(size_t)i * D_MODEL + j] = acc[m][n][r] + bias_v;
      }
    }
}

// ---------------- launcher ----------------
extern "C" void kernel_launch(void* const* d_in, const int* in_sizes, int n_in,
                              void* d_out, int out_size, void* d_ws, size_t ws_size,
                              hipStream_t stream) {
  const float* x  = (const float*)d_in[0];
  const float* cx = (const float*)d_in[1];
  const float* Wq = (const float*)d_in[2];
  const float* bq = (const float*)d_in[3];
  const float* Wk = (const float*)d_in[4];
  const float* bk = (const float*)d_in[5];
  const float* Wv = (const float*)d_in[6];
  const float* bv = (const float*)d_in[7];
  const float* Wo = (const float*)d_in[8];
  const float* bo = (const float*)d_in[9];
  float* out = (float*)d_out;
  char* ws = (char*)d_ws;

  unsigned short* Qb  = (unsigned short*)(ws + (size_t)4  * 1024 * 1024);
  unsigned short* Kb  = (unsigned short*)(ws + (size_t)8  * 1024 * 1024);
  unsigned short* Vt  = (unsigned short*)(ws + (size_t)12 * 1024 * 1024);
  unsigned short* AOb = (unsigned short*)(ws + (size_t)16 * 1024 * 1024);
  unsigned short* wb  = (unsigned short*)(ws + (size_t)21 * 1024 * 1024);

  qkv_gemm<<<dim3(64, 12), 256, 0, stream>>>(x, cx, Wq, Wk, Wv, bq, bk, bv, Qb, Kb, Vt, wb);
  attn_kernel<<<2048, 256, 0, stream>>>(Qb, Kb, Vt, wb, AOb);
  out_gemm<<<dim3(64, 4), 256, 0, stream>>>(AOb, Wo, bo, out);
}

// Round 23
// 81.596 us; speedup vs baseline: 1.3891x; 1.3799x over previous
//
#include <hip/hip_runtime.h>
#include <hip/hip_bf16.h>
#include <stdint.h>

#define D_MODEL 256
#define NHEAD   8
#define DK      32
#define BATCH   4
#define SEQ     2048
#define MROWS   (BATCH*SEQ)   // 8192

typedef float  f32x4  __attribute__((ext_vector_type(4)));
typedef __bf16 bf16x8 __attribute__((ext_vector_type(8)));

__device__ __forceinline__ unsigned short f2bf(float f) {
  unsigned int u = __float_as_uint(f);
  unsigned int r = (u + 0x7FFFu + ((u >> 16) & 1u)) >> 16;
  return (unsigned short)r;
}
__device__ __forceinline__ float bfbits2f(unsigned short b) {
  return __uint_as_float(((unsigned int)b) << 16);
}

__device__ __forceinline__ f32x4 mfma16(bf16x8 a, bf16x8 b, f32x4 c) {
  return __builtin_amdgcn_mfma_f32_16x16x32_bf16(a, b, c, 0, 0, 0);
}
__device__ __forceinline__ unsigned int cvtpk(float lo, float hi) {
  unsigned int r;
  asm("v_cvt_pk_bf16_f32 %0, %1, %2" : "=v"(r) : "v"(lo), "v"(hi));
  return r;
}

// scale folded into Wq/bq: (1/sqrt(32)) * log2(e)
#define QSCALE 0.2550599440097021f

// ---------------- fused QKV projection GEMM (128x64 tiles) -------------------
// y -> mat = y>>2 (0=Q,1=K,2=V), ncol=(y&3)*64. W casts fused into B staging;
// x cast fused into A staging. Q/K out: [bh][s][32]; V out: transposed +
// w-scaled: Vt[bh][d][s] = w_s*V[s][d]. y==0 blocks also materialize wb[].
__global__ __launch_bounds__(256) void qkv_gemm(
    const float* __restrict__ x, const float* __restrict__ cx,
    const float* __restrict__ Wq, const float* __restrict__ Wk,
    const float* __restrict__ Wv,
    const float* __restrict__ bq, const float* __restrict__ bk_, const float* __restrict__ bv,
    unsigned short* __restrict__ Qb, unsigned short* __restrict__ Kb,
    unsigned short* __restrict__ Vt, unsigned short* __restrict__ wb) {
  __shared__ __align__(16) unsigned short As[128 * 72];
  __shared__ __align__(16) unsigned short Bs[64 * 72];
  const int tid = threadIdx.x, lane = tid & 63, wid = tid >> 6;
  const int bm = blockIdx.x * 128;
  const int mat = blockIdx.y >> 2;
  const int ncol = (blockIdx.y & 3) * 64;
  const float* Wf = (mat == 0) ? Wq : ((mat == 1) ? Wk : Wv);
  const float* bias = (mat == 0) ? bq : ((mat == 1) ? bk_ : bv);
  const float bscale = (mat == 0) ? QSCALE : 1.0f;
  const int waveM = wid * 32;

  if (blockIdx.y == 0 && tid < 32) {
    int s = blockIdx.x * 32 + tid;
    wb[s] = (s == 0) ? (unsigned short)0 : f2bf(fabsf(cx[s] - cx[s - 1]));
  }

  f32x4 acc[2][4] = {};
  for (int kt = 0; kt < 4; ++kt) {
    __syncthreads();
#pragma unroll
    for (int p = 0; p < 4; ++p) {
      int c = p * 256 + tid;
      int r = c >> 3, kc = c & 7;
      const float* xp = x + (size_t)(bm + r) * 256 + kt * 64 + kc * 8;
      float4 f0 = *reinterpret_cast<const float4*>(xp);
      float4 f1 = *reinterpret_cast<const float4*>(xp + 4);
      ushort4 h0, h1;
      h0.x = f2bf(f0.x); h0.y = f2bf(f0.y); h0.z = f2bf(f0.z); h0.w = f2bf(f0.w);
      h1.x = f2bf(f1.x); h1.y = f2bf(f1.y); h1.z = f2bf(f1.z); h1.w = f2bf(f1.w);
      *reinterpret_cast<ushort4*>(&As[r * 72 + kc * 8])     = h0;
      *reinterpret_cast<ushort4*>(&As[r * 72 + kc * 8 + 4]) = h1;
    }
#pragma unroll
    for (int p = 0; p < 2; ++p) {
      int c = p * 256 + tid;
      int r = c >> 3, kc = c & 7;
      const float* wp_ = Wf + (size_t)(ncol + r) * 256 + kt * 64 + kc * 8;
      float4 g0 = *reinterpret_cast<const float4*>(wp_);
      float4 g1 = *reinterpret_cast<const float4*>(wp_ + 4);
      ushort4 b0, b1;
      b0.x = f2bf(g0.x * bscale); b0.y = f2bf(g0.y * bscale);
      b0.z = f2bf(g0.z * bscale); b0.w = f2bf(g0.w * bscale);
      b1.x = f2bf(g1.x * bscale); b1.y = f2bf(g1.y * bscale);
      b1.z = f2bf(g1.z * bscale); b1.w = f2bf(g1.w * bscale);
      *reinterpret_cast<ushort4*>(&Bs[r * 72 + kc * 8])     = b0;
      *reinterpret_cast<ushort4*>(&Bs[r * 72 + kc * 8 + 4]) = b1;
    }
    __syncthreads();
#pragma unroll
    for (int ks = 0; ks < 2; ++ks) {
      bf16x8 af[2], bf[4];
#pragma unroll
      for (int m = 0; m < 2; ++m)
        af[m] = *reinterpret_cast<const bf16x8*>(&As[(waveM + m * 16 + (lane & 15)) * 72 + ks * 32 + (lane >> 4) * 8]);
#pragma unroll
      for (int n = 0; n < 4; ++n)
        bf[n] = *reinterpret_cast<const bf16x8*>(&Bs[(n * 16 + (lane & 15)) * 72 + ks * 32 + (lane >> 4) * 8]);
#pragma unroll
      for (int m = 0; m < 2; ++m)
#pragma unroll
        for (int n = 0; n < 4; ++n) acc[m][n] = mfma16(af[m], bf[n], acc[m][n]);
    }
  }
#pragma unroll
  for (int m = 0; m < 2; ++m) {
    int i0 = bm + waveM + m * 16 + (lane >> 4) * 4;  // row of r=0 (mult of 4)
    int b = i0 >> 11, s = i0 & 2047;
    float wv4[4] = {0.f, 0.f, 0.f, 0.f};
    if (mat == 2) {
      float cm = (s > 0) ? cx[s - 1] : 0.0f;
      float c0 = cx[s], c1 = cx[s + 1], c2 = cx[s + 2], c3 = cx[s + 3];
      wv4[0] = (s > 0) ? bfbits2f(f2bf(fabsf(c0 - cm))) : 0.0f;
      wv4[1] = bfbits2f(f2bf(fabsf(c1 - c0)));
      wv4[2] = bfbits2f(f2bf(fabsf(c2 - c1)));
      wv4[3] = bfbits2f(f2bf(fabsf(c3 - c2)));
    }
#pragma unroll
    for (int n = 0; n < 4; ++n) {
      int j = ncol + n * 16 + (lane & 15);
      float bias_v = bias[j] * bscale;
      int h = j >> 5, d = j & 31;
      if (mat == 2) {
        ushort4 pk;
        pk.x = f2bf((acc[m][n][0] + bias_v) * wv4[0]);
        pk.y = f2bf((acc[m][n][1] + bias_v) * wv4[1]);
        pk.z = f2bf((acc[m][n][2] + bias_v) * wv4[2]);
        pk.w = f2bf((acc[m][n][3] + bias_v) * wv4[3]);
        *reinterpret_cast<ushort4*>(&Vt[((b * NHEAD + h) * DK + d) * SEQ + s]) = pk;
      } else {
        unsigned short* dst = (mat == 0) ? Qb : Kb;
#pragma unroll
        for (int r = 0; r < 4; ++r)
          dst[((b * NHEAD + h) * SEQ + s + r) * DK + d] = f2bf(acc[m][n][r] + bias_v);
      }
    }
  }
}

// ---------------- fused weighted attention (r8 body + XCD-affinity grid) -----
// Loop body VERBATIM round-8/14/17 (the only transport that passes AND runs at
// 55.9us — the ds_write/ds_read pair anchors the QK/PV phase split that pure
// register dataflow loses to the backend scheduler; r20-22 register path was
// correct but 87us). XCD-affinity grid: FETCH 34.8->6.2MB (free traffic win,
// time-neutral per r18 A/B).
__global__ __launch_bounds__(256, 4) void attn_kernel(
    const unsigned short* __restrict__ Qb, const unsigned short* __restrict__ Kb,
    const unsigned short* __restrict__ Vt, const unsigned short* __restrict__ wb,
    unsigned short* __restrict__ AOb) {
  __shared__ float ol[4][32][36];
  __shared__ __align__(16) unsigned short ps[4][2][32][40];
  const int tid = threadIdx.x, lane = tid & 63, wid = tid >> 6;
  const int g = lane >> 4, lq = lane & 15;

  // XCD-affinity decode: xcd = bid%8 serves bh in [4*xcd, 4*xcd+4)
  const int bid = blockIdx.x;
  const int xcd = bid & 7, slot = bid >> 3;        // 256 slots per XCD
  const int bh = xcd * 4 + (slot >> 6);
  const int q0 = (slot & 63) * 32;

  const unsigned short* Qbh = Qb + bh * SEQ * DK;
  const unsigned short* Kbh = Kb + bh * SEQ * DK;
  const unsigned short* Vbh = Vt + bh * DK * SEQ;

  bf16x8 qf[2];
  qf[0] = *reinterpret_cast<const bf16x8*>(Qbh + (q0 + lq) * DK + g * 8);
  qf[1] = *reinterpret_cast<const bf16x8*>(Qbh + (q0 + 16 + lq) * DK + g * 8);

  f32x4 o[2][2] = {};   // [q-tile m][d-tile n]
  f32x4 den[2] = {};
  const f32x4 zero4 = {0.f, 0.f, 0.f, 0.f};
  const int sbase = wid * (SEQ / 4);

#pragma unroll 2
  for (int st = 0; st < (SEQ / 4) / 32; ++st) {
    const int s0 = sbase + st * 32;
    bf16x8 kf0 = *reinterpret_cast<const bf16x8*>(Kbh + (s0 + lq) * DK + g * 8);
    bf16x8 kf1 = *reinterpret_cast<const bf16x8*>(Kbh + (s0 + 16 + lq) * DK + g * 8);

    unsigned short* pb = &ps[wid][st & 1][0][0];

#pragma unroll
    for (int m = 0; m < 2; ++m) {
      f32x4 sc0 = mfma16(kf0, qf[m], zero4);
      f32x4 sc1 = mfma16(kf1, qf[m], zero4);
      uint2 w0, w1;
      w0.x = cvtpk(__builtin_amdgcn_exp2f(sc0[0]), __builtin_amdgcn_exp2f(sc0[1]));
      w0.y = cvtpk(__builtin_amdgcn_exp2f(sc0[2]), __builtin_amdgcn_exp2f(sc0[3]));
      w1.x = cvtpk(__builtin_amdgcn_exp2f(sc1[0]), __builtin_amdgcn_exp2f(sc1[1]));
      w1.y = cvtpk(__builtin_amdgcn_exp2f(sc1[2]), __builtin_amdgcn_exp2f(sc1[3]));
      *reinterpret_cast<uint2*>(pb + (16 * m + lq) * 40 + g * 4)      = w0;
      *reinterpret_cast<uint2*>(pb + (16 * m + lq) * 40 + 16 + g * 4) = w1;
    }

    bf16x8 vf0 = *reinterpret_cast<const bf16x8*>(Vbh + (lq)      * SEQ + s0 + g * 8);
    bf16x8 vf1 = *reinterpret_cast<const bf16x8*>(Vbh + (16 + lq) * SEQ + s0 + g * 8);
    bf16x8 wf  = *reinterpret_cast<const bf16x8*>(wb + s0 + g * 8);

#pragma unroll
    for (int m = 0; m < 2; ++m) {
      bf16x8 pa = *reinterpret_cast<const bf16x8*>(pb + (16 * m + lq) * 40 + g * 8);
      o[m][0] = mfma16(pa, vf0, o[m][0]);
      o[m][1] = mfma16(pa, vf1, o[m][1]);
      den[m]  = mfma16(pa, wf,  den[m]);
    }
  }

  // stash partials into ol[wid]: [q32][d], denominator in col 32
#pragma unroll
  for (int m = 0; m < 2; ++m) {
#pragma unroll
    for (int r = 0; r < 4; ++r) {
      int q32 = 16 * m + 4 * g + r;
      ol[wid][q32][lq]      = o[m][0][r];
      ol[wid][q32][16 + lq] = o[m][1][r];
      if (lq == 0) ol[wid][q32][32] = den[m][r];
    }
  }
  __syncthreads();

  const int b = bh >> 3, h = bh & 7;
  for (int idx = tid; idx < 32 * 32; idx += 256) {
    int q = idx >> 5, d = idx & 31;
    float num = ol[0][q][d] + ol[1][q][d] + ol[2][q][d] + ol[3][q][d];
    float dd  = ol[0][q][32] + ol[1][q][32] + ol[2][q][32] + ol[3][q][32];
    AOb[(b * SEQ + q0 + q) * D_MODEL + h * DK + d] = f2bf(num / dd);
  }
}

// ---------------- output projection GEMM (128x64 tiles, full CU coverage) ----
__global__ __launch_bounds__(256) void out_gemm(
    const unsigned short* __restrict__ Ab, const float* __restrict__ Wo,
    const float* __restrict__ bo, float* __restrict__ out) {
  __shared__ __align__(16) unsigned short As[128 * 72];
  __shared__ __align__(16) unsigned short Bs[64 * 72];
  const int tid = threadIdx.x, lane = tid & 63, wid = tid >> 6;
  const int bm = blockIdx.x * 128;
  const int ncol = blockIdx.y * 64;
  const int waveM = wid * 32;

  f32x4 acc[2][4] = {};
  for (int kt = 0; kt < 4; ++kt) {
    __syncthreads();
#pragma unroll
    for (int p = 0; p < 4; ++p) {
      int c = p * 256 + tid;
      int r = c >> 3, kc = c & 7;
      uint4 va = *reinterpret_cast<const uint4*>(Ab + (size_t)(bm + r) * 256 + kt * 64 + kc * 8);
      *reinterpret_cast<uint4*>(&As[r * 72 + kc * 8]) = va;
    }
#pragma unroll
    for (int p = 0; p < 2; ++p) {
      int c = p * 256 + tid;
      int r = c >> 3, kc = c & 7;
      const float* wp_ = Wo + (size_t)(ncol + r) * 256 + kt * 64 + kc * 8;
      float4 g0 = *reinterpret_cast<const float4*>(wp_);
      float4 g1 = *reinterpret_cast<const float4*>(wp_ + 4);
      ushort4 b0, b1;
      b0.x = f2bf(g0.x); b0.y = f2bf(g0.y); b0.z = f2bf(g0.z); b0.w = f2bf(g0.w);
      b1.x = f2bf(g1.x); b1.y = f2bf(g1.y); b1.z = f2bf(g1.z); b1.w = f2bf(g1.w);
      *reinterpret_cast<ushort4*>(&Bs[r * 72 + kc * 8])     = b0;
      *reinterpret_cast<ushort4*>(&Bs[r * 72 + kc * 8 + 4]) = b1;
    }
    __syncthreads();
#pragma unroll
    for (int ks = 0; ks < 2; ++ks) {
      bf16x8 af[2], bf[4];
#pragma unroll
      for (int m = 0; m < 2; ++m)
        af[m] = *reinterpret_cast<const bf16x8*>(&As[(waveM + m * 16 + (lane & 15)) * 72 + ks * 32 + (lane >> 4) * 8]);
#pragma unroll
      for (int n = 0; n < 4; ++n)
        bf[n] = *reinterpret_cast<const bf16x8*>(&Bs[(n * 16 + (lane & 15)) * 72 + ks * 32 + (lane >> 4) * 8]);
#pragma unroll
      for (int m = 0; m < 2; ++m)
#pragma unroll
        for (int n = 0; n < 4; ++n) acc[m][n] = mfma16(af[m], bf[n], acc[m][n]);
    }
  }
#pragma unroll
  for (int m = 0; m < 2; ++m)
#pragma unroll
    for (int n = 0; n < 4; ++n) {
      int j = ncol + n * 16 + (lane & 15);
      float bias_v = bo[j];
#pragma unroll
      for (int r = 0; r < 4; ++r) {
        int i = bm + waveM + m * 16 + (lane >> 4) * 4 + r;
        out[(size_t)i * D_MODEL + j] = acc[m][n][r] + bias_v;
      }
    }
}

// ---------------- launcher ----------------
extern "C" void kernel_launch(void* const* d_in, const int* in_sizes, int n_in,
                              void* d_out, int out_size, void* d_ws, size_t ws_size,
                              hipStream_t stream) {
  const float* x  = (const float*)d_in[0];
  const float* cx = (const float*)d_in[1];
  const float* Wq = (const float*)d_in[2];
  const float* bq = (const float*)d_in[3];
  const float* Wk = (const float*)d_in[4];
  const float* bk = (const float*)d_in[5];
  const float* Wv = (const float*)d_in[6];
  const float* bv = (const float*)d_in[7];
  const float* Wo = (const float*)d_in[8];
  const float* bo = (const float*)d_in[9];
  float* out = (float*)d_out;
  char* ws = (char*)d_ws;

  unsigned short* Qb  = (unsigned short*)(ws + (size_t)4  * 1024 * 1024);
  unsigned short* Kb  = (unsigned short*)(ws + (size_t)8  * 1024 * 1024);
  unsigned short* Vt  = (unsigned short*)(ws + (size_t)12 * 1024 * 1024);
  unsigned short* AOb = (unsigned short*)(ws + (size_t)16 * 1024 * 1024);
  unsigned short* wb  = (unsigned short*)(ws + (size_t)21 * 1024 * 1024);

  qkv_gemm<<<dim3(64, 12), 256, 0, stream>>>(x, cx, Wq, Wk, Wv, bq, bk, bv, Qb, Kb, Vt, wb);
  attn_kernel<<<2048, 256, 0, stream>>>(Qb, Kb, Vt, wb, AOb);
  out_gemm<<<dim3(64, 4), 256, 0, stream>>>(AOb, Wo, bo, out);
}